// Round 11
// baseline (253.879 us; speedup 1.0000x reference)
//
#include <hip/hip_runtime.h>
#include <cstdint>
#include <cstddef>

// Problem constants (fixed by setup_inputs)
#define NB 4      // batch
#define NT 12     // timesteps
#define NN 2048   // nodes
#define NF 64     // in features
#define NH 4      // heads
#define ND 16     // head dim
#define NC 64     // out channels
#define MAXD 64   // max neighbors kept (Binomial(2047,16/2048): P(deg>64)~1e-19)
#define NR (NB * NT * NN)  // 98304 batched GEMM rows

typedef _Float16 f16x8 __attribute__((ext_vector_type(8)));
typedef _Float16 f16x2 __attribute__((ext_vector_type(2)));
typedef float f32x4 __attribute__((ext_vector_type(4)));

#define LR(v) ((v) >= 0.f ? (v) : 0.2f * (v))
#define RCPF(x) __builtin_amdgcn_rcpf(x)

// ---------------------------------------------------------------------------
// Build padded adjacency lists from the additive mask (0 / -1e9), one wave/row.
__global__ __launch_bounds__(256) void build_adj_k(const float* __restrict__ bias,
                                                   int* __restrict__ adj,
                                                   int* __restrict__ deg) {
  int gtid = blockIdx.x * 256 + threadIdx.x;
  int wid = gtid >> 6;            // row id in [0, NB*NN)
  int lane = threadIdx.x & 63;
  if (wid >= NB * NN) return;
  const float* row = bias + (size_t)wid * NN;
  int* arow = adj + (size_t)wid * MAXD;
  int count = 0;
  for (int c0 = 0; c0 < NN; c0 += 64) {
    float v = __builtin_nontemporal_load(row + c0 + lane);  // 67 MB single-use
    bool e = (v > -1e8f);                       // edge iff mask == 0
    unsigned long long m = __ballot(e);
    int pre = __popcll(m & ((1ull << lane) - 1ull));
    if (e) {
      int pos = count + pre;
      if (pos < MAXD) arow[pos] = c0 + lane;
    }
    count += __popcll(m);
  }
  if (lane == 0) deg[wid] = count < MAXD ? count : MAXD;
}

// ---------------------------------------------------------------------------
// One-shot weight prep: fp16 W16[272][64] in B-fragment layout + biasC[128].
// Cols: 0..63 Wgz | 64..127 Wgh | 128..191 Wz | 192..255 Wh |
//       256..271 vproj (Wg . a): j = [f1z(4)|f1h(4)|f2z(4)|f2h(4)], h = j&3.
__global__ __launch_bounds__(256) void prep_w_k(
    const float* __restrict__ Wgz, const float* __restrict__ Wgh,
    const float* __restrict__ Wz,  const float* __restrict__ Wh,
    const float* __restrict__ a1z, const float* __restrict__ a2z,
    const float* __restrict__ a1h, const float* __restrict__ a2h,
    const float* __restrict__ Zb,  const float* __restrict__ Hb,
    _Float16* __restrict__ W16, float* __restrict__ biasC) {
  int idx = blockIdx.x * 256 + threadIdx.x;
  if (idx < 272 * 64) {
    int c = idx >> 6, k = idx & 63;
    float w;
    if (c < 64)       w = Wgz[((c >> 4) << 10) + (k << 4) + (c & 15)];
    else if (c < 128) { int q = c - 64; w = Wgh[((q >> 4) << 10) + (k << 4) + (q & 15)]; }
    else if (c < 192) w = Wz[(k << 6) + (c - 128)];
    else if (c < 256) w = Wh[(k << 6) + (c - 192)];
    else {
      int j = c - 256, h = j & 3;
      const float* Wg = (j & 4) ? Wgh : Wgz;
      const float* av = (j & 8) ? ((j & 4) ? a2h : a2z) : ((j & 4) ? a1h : a1z);
      float s = 0.f;
#pragma unroll
      for (int d = 0; d < 16; d++)
        s = fmaf(Wg[(h << 10) + (k << 4) + d], av[(h << 4) + d], s);
      w = s;
    }
    W16[idx] = (_Float16)w;
  }
  if (blockIdx.x == 0 && threadIdx.x < 128)
    biasC[threadIdx.x] =
        (threadIdx.x < 64) ? Zb[threadIdx.x] : Hb[threadIdx.x - 64];
}

// ---------------------------------------------------------------------------
// fp16 MFMA GEMM: [98304 x 64] @ [64 x 272], fp32 accumulate. A-frags from X
// (cvt in regs); B-frags from global W16 (L1/L2-resident). Wave = 16 rows x
// 17 col-tiles x K=64. Epilogue: per-wave LDS transpose (stride 68: 2-way
// bank alias = free) then 4 coalesced dwordx4 stores per buffer (16 lanes =
// one full 256 B row each).
__global__ __launch_bounds__(256) void mfma_gemm_k(
    const float* __restrict__ X, const _Float16* __restrict__ W16,
    const float* __restrict__ biasC,
    uint32_t* __restrict__ gbufF, uint32_t* __restrict__ gbufS,
    float* __restrict__ fbuf) {
  __shared__ uint32_t tr[4][16 * 68];   // per-wave 16 rows x 64 cols (+pad)
  const int tid = threadIdx.x;
  const int wv = tid >> 6, lane = tid & 63;
  const int m = lane & 15, quad = lane >> 4;
  const unsigned rw = blockIdx.x * 64 + wv * 16;      // wave's row base
  uint32_t* tw = tr[wv];

  const float* xr = X + (size_t)(rw + m) * 64;
  float4 x0 = *(const float4*)(xr + quad * 8);
  float4 x1 = *(const float4*)(xr + quad * 8 + 4);
  float4 x2 = *(const float4*)(xr + 32 + quad * 8);
  float4 x3 = *(const float4*)(xr + 32 + quad * 8 + 4);
  f16x8 A0 = {(_Float16)x0.x, (_Float16)x0.y, (_Float16)x0.z, (_Float16)x0.w,
              (_Float16)x1.x, (_Float16)x1.y, (_Float16)x1.z, (_Float16)x1.w};
  f16x8 A1 = {(_Float16)x2.x, (_Float16)x2.y, (_Float16)x2.z, (_Float16)x2.w,
              (_Float16)x3.x, (_Float16)x3.y, (_Float16)x3.z, (_Float16)x3.w};

  float bzc[4], bhc[4];
#pragma unroll
  for (int j = 0; j < 4; j++) {
    bzc[j] = biasC[j * 16 + m];
    bhc[j] = biasC[64 + j * 16 + m];
  }
  const int rsub = lane >> 4, chk = lane & 15;   // readback: row-sub, chunk

  f32x4 zacc[4], zs[4];
#pragma unroll
  for (int ct = 0; ct < 17; ct++) {
    const _Float16* wp = W16 + (ct * 16 + m) * 64;
    f16x8 B0 = *(const f16x8*)(wp + quad * 8);
    f16x8 B1 = *(const f16x8*)(wp + 32 + quad * 8);
    f32x4 acc = {0.f, 0.f, 0.f, 0.f};
    acc = __builtin_amdgcn_mfma_f32_16x16x32_f16(A0, B0, acc, 0, 0, 0);
    acc = __builtin_amdgcn_mfma_f32_16x16x32_f16(A1, B1, acc, 0, 0, 0);
    // C-layout: row = quad*4 + r, col = ct*16 + m  [measured: learn_hip m89]
    if (ct < 4) {
      zacc[ct] = acc;                        // z-feat tiles, saved for pairing
    } else if (ct < 8) {
      const int j = ct - 4;                  // h-feat tile -> pack {z,h}
#pragma unroll
      for (int r = 0; r < 4; r++) {
        f16x2 pv = {(_Float16)zacc[j][r], (_Float16)acc[r]};
        tw[(quad * 4 + r) * 68 + j * 16 + m] = __builtin_bit_cast(uint32_t, pv);
      }
      if (ct == 7) {   // full-tile readback: 4 stores x (16 lanes = 256B row)
#pragma unroll
        for (int i = 0; i < 4; i++) {
          int row = i * 4 + rsub;
          uint4 v = *(const uint4*)&tw[row * 68 + chk * 4];
          *(uint4*)&gbufF[(size_t)(rw + row) * 64 + chk * 4] = v;
        }
      }
    } else if (ct < 12) {
#pragma unroll
      for (int r = 0; r < 4; r++) zs[ct - 8][r] = acc[r] + bzc[ct - 8];
    } else if (ct < 16) {
      const int j = ct - 12;
#pragma unroll
      for (int r = 0; r < 4; r++) {
        f16x2 pv = {(_Float16)zs[j][r], (_Float16)(acc[r] + bhc[j])};
        tw[(quad * 4 + r) * 68 + j * 16 + m] = __builtin_bit_cast(uint32_t, pv);
      }
      if (ct == 15) {
#pragma unroll
        for (int i = 0; i < 4; i++) {
          int row = i * 4 + rsub;
          uint4 v = *(const uint4*)&tw[row * 68 + chk * 4];
          *(uint4*)&gbufS[(size_t)(rw + row) * 64 + chk * 4] = v;
        }
      }
    } else {
      const unsigned rb = rw + quad * 4;
#pragma unroll
      for (int r = 0; r < 4; r++) fbuf[(size_t)(rb + r) * 16 + m] = acc[r];
    }
  }
}

// ---------------------------------------------------------------------------
// Attention: one wave per (node, t-PAIR). R10 was VALU-bound (VALUBusy 90%)
// with much per-neighbor work t-invariant — pairing t,t+1 in one wave shares
// the adjacency row, gather voffsets, and loop control across 2 timesteps
// (~25-30% fewer VALU instr/unit-work; extra loads go to the 33%-utilized
// memory pipe). Grid = (node-groups, t-pair) keeps co-resident working set to
// 2 adjacent t-slabs. Phase 1 (lane = neighbor, exec-masked): raw exp
// weights for both t -> LDS. Phase 2 (lane = channel): shared-offset dual-t
// 8-wide gather with in-loop norm sums; ELU + self epilogue per t.
__global__ __launch_bounds__(256) void attn_k(
    const uint32_t* __restrict__ gbufF, const uint32_t* __restrict__ gbufS,
    const float* __restrict__ fbuf,
    const int* __restrict__ adj, const int* __restrict__ deg,
    const float* __restrict__ bgz, const float* __restrict__ bgh,
    float2* __restrict__ abuf) {
  __shared__ int adjL[4][MAXD];         // 1 KB
  __shared__ float wexp[4][2][8][68];   // 17.4 KB; stride 68 kills head-alias
  const int tid = threadIdx.x;
  const int lane = tid & 63;
  const int ws = tid >> 6;
  const int node = blockIdx.x * 4 + ws;
  const int t0 = blockIdx.y * 2;        // pair (t0, t0+1)
  const int b = node >> 11;
  const int nl = node & (NN - 1);
  const int dg = deg[node];
  adjL[ws][lane] = (lane < dg) ? adj[node * MAXD + lane] : 0;
  const int dgp = (dg + 7) & ~7;        // padded slots have weight 0 -> inert

  const unsigned rb0 = (unsigned)(b * NT + t0) * NN;
  const float* fb0 = fbuf + (size_t)rb0 * 16;
  const float* fb1 = fb0 + (size_t)NN * 16;
  const uint32_t* gF0 = gbufF + (size_t)rb0 * 64;
  const uint32_t* gF1 = gF0 + (size_t)NN * 64;
  const uint32_t* gS0 = gbufS + (size_t)rb0 * 64;
  const uint32_t* gS1 = gS0 + (size_t)NN * 64;
  const int ch = lane, hh = lane >> 4;

  // ---- phase 1: raw exp attention weights, both t (lane = neighbor) ----
  {
    const float4* p0 = (const float4*)(fb0 + nl * 16);
    const float4* p1 = (const float4*)(fb1 + nl * 16);
    float4 f1z0 = p0[0], f1h0 = p0[1];
    float4 f1z1 = p1[0], f1h1 = p1[1];
    if (lane < dg) {                    // exec-masked: inactive lanes load 0 B
      int mm = adjL[ws][lane];
      const float4* q0 = (const float4*)(fb0 + mm * 16);
      const float4* q1 = (const float4*)(fb1 + mm * 16);
      float4 f2z0 = q0[2], f2h0 = q0[3];
      float4 f2z1 = q1[2], f2h1 = q1[3];
      wexp[ws][0][0][lane] = __expf(LR(f1z0.x + f2z0.x));
      wexp[ws][0][1][lane] = __expf(LR(f1z0.y + f2z0.y));
      wexp[ws][0][2][lane] = __expf(LR(f1z0.z + f2z0.z));
      wexp[ws][0][3][lane] = __expf(LR(f1z0.w + f2z0.w));
      wexp[ws][0][4][lane] = __expf(LR(f1h0.x + f2h0.x));
      wexp[ws][0][5][lane] = __expf(LR(f1h0.y + f2h0.y));
      wexp[ws][0][6][lane] = __expf(LR(f1h0.z + f2h0.z));
      wexp[ws][0][7][lane] = __expf(LR(f1h0.w + f2h0.w));
      wexp[ws][1][0][lane] = __expf(LR(f1z1.x + f2z1.x));
      wexp[ws][1][1][lane] = __expf(LR(f1z1.y + f2z1.y));
      wexp[ws][1][2][lane] = __expf(LR(f1z1.z + f2z1.z));
      wexp[ws][1][3][lane] = __expf(LR(f1z1.w + f2z1.w));
      wexp[ws][1][4][lane] = __expf(LR(f1h1.x + f2h1.x));
      wexp[ws][1][5][lane] = __expf(LR(f1h1.y + f2h1.y));
      wexp[ws][1][6][lane] = __expf(LR(f1h1.z + f2h1.z));
      wexp[ws][1][7][lane] = __expf(LR(f1h1.w + f2h1.w));
    } else {
#pragma unroll
      for (int k = 0; k < 8; k++) {
        wexp[ws][0][k][lane] = 0.f;
        wexp[ws][1][k][lane] = 0.f;
      }
    }
  }

  // ---- phase 2: dual-t 8-wide gather with shared offsets ----
  float az0 = 0.f, ah0 = 0.f, sz0 = 0.f, sh0 = 0.f;
  float az1 = 0.f, ah1 = 0.f, sz1 = 0.f, sh1 = 0.f;
  const float* wz0 = wexp[ws][0][hh];
  const float* wh0 = wexp[ws][0][4 + hh];
  const float* wz1 = wexp[ws][1][hh];
  const float* wh1 = wexp[ws][1][4 + hh];
  for (int mi = 0; mi < dgp; mi += 8) {
    int4 ma = *(const int4*)&adjL[ws][mi];
    int4 mb = *(const int4*)&adjL[ws][mi + 4];
    int o0 = (ma.x << 6) + ch, o1 = (ma.y << 6) + ch;
    int o2 = (ma.z << 6) + ch, o3 = (ma.w << 6) + ch;
    int o4 = (mb.x << 6) + ch, o5 = (mb.y << 6) + ch;
    int o6 = (mb.z << 6) + ch, o7 = (mb.w << 6) + ch;
    uint32_t a0 = gF0[o0], a1 = gF0[o1], a2 = gF0[o2], a3 = gF0[o3];
    uint32_t a4 = gF0[o4], a5 = gF0[o5], a6 = gF0[o6], a7 = gF0[o7];
    uint32_t c0 = gF1[o0], c1 = gF1[o1], c2 = gF1[o2], c3 = gF1[o3];
    uint32_t c4 = gF1[o4], c5 = gF1[o5], c6 = gF1[o6], c7 = gF1[o7];
    float4 wza = *(const float4*)&wz0[mi], wzb = *(const float4*)&wz0[mi + 4];
    float4 wha = *(const float4*)&wh0[mi], whb = *(const float4*)&wh0[mi + 4];
    float4 wzc = *(const float4*)&wz1[mi], wzd = *(const float4*)&wz1[mi + 4];
    float4 whc = *(const float4*)&wh1[mi], whd = *(const float4*)&wh1[mi + 4];
    f16x2 p0 = __builtin_bit_cast(f16x2, a0), p1 = __builtin_bit_cast(f16x2, a1);
    f16x2 p2 = __builtin_bit_cast(f16x2, a2), p3 = __builtin_bit_cast(f16x2, a3);
    f16x2 p4 = __builtin_bit_cast(f16x2, a4), p5 = __builtin_bit_cast(f16x2, a5);
    f16x2 p6 = __builtin_bit_cast(f16x2, a6), p7 = __builtin_bit_cast(f16x2, a7);
    f16x2 q0 = __builtin_bit_cast(f16x2, c0), q1 = __builtin_bit_cast(f16x2, c1);
    f16x2 q2 = __builtin_bit_cast(f16x2, c2), q3 = __builtin_bit_cast(f16x2, c3);
    f16x2 q4 = __builtin_bit_cast(f16x2, c4), q5 = __builtin_bit_cast(f16x2, c5);
    f16x2 q6 = __builtin_bit_cast(f16x2, c6), q7 = __builtin_bit_cast(f16x2, c7);
    az0 = fmaf(wza.x, (float)p0.x, az0); ah0 = fmaf(wha.x, (float)p0.y, ah0);
    az0 = fmaf(wza.y, (float)p1.x, az0); ah0 = fmaf(wha.y, (float)p1.y, ah0);
    az0 = fmaf(wza.z, (float)p2.x, az0); ah0 = fmaf(wha.z, (float)p2.y, ah0);
    az0 = fmaf(wza.w, (float)p3.x, az0); ah0 = fmaf(wha.w, (float)p3.y, ah0);
    az0 = fmaf(wzb.x, (float)p4.x, az0); ah0 = fmaf(whb.x, (float)p4.y, ah0);
    az0 = fmaf(wzb.y, (float)p5.x, az0); ah0 = fmaf(whb.y, (float)p5.y, ah0);
    az0 = fmaf(wzb.z, (float)p6.x, az0); ah0 = fmaf(whb.z, (float)p6.y, ah0);
    az0 = fmaf(wzb.w, (float)p7.x, az0); ah0 = fmaf(whb.w, (float)p7.y, ah0);
    az1 = fmaf(wzc.x, (float)q0.x, az1); ah1 = fmaf(whc.x, (float)q0.y, ah1);
    az1 = fmaf(wzc.y, (float)q1.x, az1); ah1 = fmaf(whc.y, (float)q1.y, ah1);
    az1 = fmaf(wzc.z, (float)q2.x, az1); ah1 = fmaf(whc.z, (float)q2.y, ah1);
    az1 = fmaf(wzc.w, (float)q3.x, az1); ah1 = fmaf(whc.w, (float)q3.y, ah1);
    az1 = fmaf(wzd.x, (float)q4.x, az1); ah1 = fmaf(whd.x, (float)q4.y, ah1);
    az1 = fmaf(wzd.y, (float)q5.x, az1); ah1 = fmaf(whd.y, (float)q5.y, ah1);
    az1 = fmaf(wzd.z, (float)q6.x, az1); ah1 = fmaf(whd.z, (float)q6.y, ah1);
    az1 = fmaf(wzd.w, (float)q7.x, az1); ah1 = fmaf(whd.w, (float)q7.y, ah1);
    sz0 += (wza.x + wza.y) + (wza.z + wza.w) + (wzb.x + wzb.y) + (wzb.z + wzb.w);
    sh0 += (wha.x + wha.y) + (wha.z + wha.w) + (whb.x + whb.y) + (whb.z + whb.w);
    sz1 += (wzc.x + wzc.y) + (wzc.z + wzc.w) + (wzd.x + wzd.y) + (wzd.z + wzd.w);
    sh1 += (whc.x + whc.y) + (whc.z + whc.w) + (whd.x + whd.y) + (whd.z + whd.w);
  }
  az0 *= RCPF(sz0); ah0 *= RCPF(sh0);
  az1 *= RCPF(sz1); ah1 *= RCPF(sh1);

  // ---- epilogue: ELU + bias + self term -> pre-gate values (fp32) ----
  const float bz = bgz[ch], bh = bgh[ch];
  {
    f16x2 sp = __builtin_bit_cast(f16x2, gS0[(nl << 6) + ch]);
    float vz = az0 + bz; vz = vz > 0.f ? vz : __expf(vz) - 1.f;
    float vh = ah0 + bh; vh = vh > 0.f ? vh : __expf(vh) - 1.f;
    abuf[(size_t)(rb0 + nl) * 64 + ch] =
        make_float2(vz + (float)sp.x, vh + (float)sp.y);
  }
  {
    f16x2 sp = __builtin_bit_cast(f16x2, gS1[(nl << 6) + ch]);
    float vz = az1 + bz; vz = vz > 0.f ? vz : __expf(vz) - 1.f;
    float vh = ah1 + bh; vh = vh > 0.f ? vh : __expf(vh) - 1.f;
    abuf[(size_t)(rb0 + NN + nl) * 64 + ch] =
        make_float2(vz + (float)sp.x, vh + (float)sp.y);
  }
}

// ---------------------------------------------------------------------------
// GRU recurrence: one lane per (node, channel); 12-step serial chain on
// pre-gate values. Memory-bound (50 MB coalesced read). BN fused at the end.
__global__ __launch_bounds__(256) void gru_k(
    const float2* __restrict__ abuf,
    const float* __restrict__ gam, const float* __restrict__ bet,
    const float* __restrict__ mu, const float* __restrict__ var,
    float* __restrict__ out) {
  const int gtid = blockIdx.x * 256 + threadIdx.x;   // [0, NB*NN*64)
  const int node = gtid >> 6, ch = gtid & 63;
  const int b = node >> 11, nl = node & (NN - 1);
  float hc = 0.f;
#pragma unroll
  for (int t = 0; t < NT; t++) {
    float2 pre = abuf[(size_t)((b * NT + t) * NN + nl) * 64 + ch];
    float zg = RCPF(1.f + __expf(-(pre.x + hc)));             // sigmoid
    float ta = pre.y + hc;
    float tg = 1.f - 2.f * RCPF(__expf(2.f * ta) + 1.f);      // tanh
    hc = zg * hc + (1.f - zg) * tg;
  }
  out[gtid] = (hc - mu[ch]) * rsqrtf(var[ch] + 1e-3f) * gam[ch] + bet[ch];
}

// ---------------------------------------------------------------------------
extern "C" void kernel_launch(void* const* d_in, const int* in_sizes, int n_in,
                              void* d_out, int out_size, void* d_ws, size_t ws_size,
                              hipStream_t stream) {
  (void)in_sizes; (void)n_in; (void)out_size; (void)ws_size;
  const float* X   = (const float*)d_in[0];
  const float* bm  = (const float*)d_in[1];
  const float* Wz  = (const float*)d_in[2];
  const float* Zb  = (const float*)d_in[3];
  const float* Wh  = (const float*)d_in[4];
  const float* Hb  = (const float*)d_in[5];
  const float* Wgz = (const float*)d_in[6];
  const float* a1z = (const float*)d_in[7];
  const float* a2z = (const float*)d_in[8];
  const float* bgz = (const float*)d_in[9];
  const float* Wgh = (const float*)d_in[10];
  const float* a1h = (const float*)d_in[11];
  const float* a2h = (const float*)d_in[12];
  const float* bgh = (const float*)d_in[13];
  const float* gam = (const float*)d_in[14];
  const float* bet = (const float*)d_in[15];
  const float* mu  = (const float*)d_in[16];
  const float* var = (const float*)d_in[17];
  float* out = (float*)d_out;

  char* p = (char*)d_ws;
  uint32_t* gbufF = (uint32_t*)p; p += (size_t)NR * 64 * sizeof(uint32_t);  // 25 MB
  uint32_t* gbufS = (uint32_t*)p; p += (size_t)NR * 64 * sizeof(uint32_t);  // 25 MB
  float*    fbuf  = (float*)p;    p += (size_t)NR * 16 * sizeof(float);     // 6 MB
  float2*   abuf  = (float2*)p;   p += (size_t)NR * 64 * sizeof(float2);    // 50 MB
  int*      adj   = (int*)p;      p += (size_t)NB * NN * MAXD * sizeof(int);// 2 MB
  int*      deg   = (int*)p;      p += (size_t)NB * NN * sizeof(int);       // 32 KB
  _Float16* W16   = (_Float16*)p; p += 272 * 64 * sizeof(_Float16);         // 34 KB
  float*    biasC = (float*)p;    p += 128 * sizeof(float);

  prep_w_k<<<dim3(68), dim3(256), 0, stream>>>(
      Wgz, Wgh, Wz, Wh, a1z, a2z, a1h, a2h, Zb, Hb, W16, biasC);
  build_adj_k<<<dim3(NB * NN / 4), dim3(256), 0, stream>>>(bm, adj, deg);
  mfma_gemm_k<<<dim3(NR / 64), dim3(256), 0, stream>>>(
      X, W16, biasC, gbufF, gbufS, fbuf);
  attn_k<<<dim3(NB * NN / 4, NT / 2), dim3(256), 0, stream>>>(
      gbufF, gbufS, fbuf, adj, deg, bgz, bgh, abuf);
  gru_k<<<dim3(NB * NN * 64 / 256), dim3(256), 0, stream>>>(
      abuf, gam, bet, mu, var, out);
}

// Round 12
// 246.089 us; speedup vs baseline: 1.0317x; 1.0317x over previous
//
#include <hip/hip_runtime.h>
#include <cstdint>
#include <cstddef>

// Problem constants (fixed by setup_inputs)
#define NB 4      // batch
#define NT 12     // timesteps
#define NN 2048   // nodes
#define NF 64     // in features
#define NH 4      // heads
#define ND 16     // head dim
#define NC 64     // out channels
#define MAXD 64   // max neighbors kept (Binomial(2047,16/2048): P(deg>64)~1e-19)
#define NR (NB * NT * NN)  // 98304 batched GEMM rows

typedef _Float16 f16x8 __attribute__((ext_vector_type(8)));
typedef _Float16 f16x2 __attribute__((ext_vector_type(2)));
typedef float f32x4 __attribute__((ext_vector_type(4)));

#define LR(v) ((v) >= 0.f ? (v) : 0.2f * (v))
#define RCPF(x) __builtin_amdgcn_rcpf(x)

// ---------------------------------------------------------------------------
// Build padded adjacency lists from the additive mask (0 / -1e9), one wave/row.
__global__ __launch_bounds__(256) void build_adj_k(const float* __restrict__ bias,
                                                   int* __restrict__ adj,
                                                   int* __restrict__ deg) {
  int gtid = blockIdx.x * 256 + threadIdx.x;
  int wid = gtid >> 6;            // row id in [0, NB*NN)
  int lane = threadIdx.x & 63;
  if (wid >= NB * NN) return;
  const float* row = bias + (size_t)wid * NN;
  int* arow = adj + (size_t)wid * MAXD;
  int count = 0;
  for (int c0 = 0; c0 < NN; c0 += 64) {
    float v = __builtin_nontemporal_load(row + c0 + lane);  // 67 MB single-use
    bool e = (v > -1e8f);                       // edge iff mask == 0
    unsigned long long m = __ballot(e);
    int pre = __popcll(m & ((1ull << lane) - 1ull));
    if (e) {
      int pos = count + pre;
      if (pos < MAXD) arow[pos] = c0 + lane;
    }
    count += __popcll(m);
  }
  if (lane == 0) deg[wid] = count < MAXD ? count : MAXD;
}

// ---------------------------------------------------------------------------
// One-shot weight prep: fp16 W16[272][64] in B-fragment layout + biasC[128].
// Cols: 0..63 Wgz | 64..127 Wgh | 128..191 Wz | 192..255 Wh |
//       256..271 vproj (Wg . a): j = [f1z(4)|f1h(4)|f2z(4)|f2h(4)], h = j&3.
__global__ __launch_bounds__(256) void prep_w_k(
    const float* __restrict__ Wgz, const float* __restrict__ Wgh,
    const float* __restrict__ Wz,  const float* __restrict__ Wh,
    const float* __restrict__ a1z, const float* __restrict__ a2z,
    const float* __restrict__ a1h, const float* __restrict__ a2h,
    const float* __restrict__ Zb,  const float* __restrict__ Hb,
    _Float16* __restrict__ W16, float* __restrict__ biasC) {
  int idx = blockIdx.x * 256 + threadIdx.x;
  if (idx < 272 * 64) {
    int c = idx >> 6, k = idx & 63;
    float w;
    if (c < 64)       w = Wgz[((c >> 4) << 10) + (k << 4) + (c & 15)];
    else if (c < 128) { int q = c - 64; w = Wgh[((q >> 4) << 10) + (k << 4) + (q & 15)]; }
    else if (c < 192) w = Wz[(k << 6) + (c - 128)];
    else if (c < 256) w = Wh[(k << 6) + (c - 192)];
    else {
      int j = c - 256, h = j & 3;
      const float* Wg = (j & 4) ? Wgh : Wgz;
      const float* av = (j & 8) ? ((j & 4) ? a2h : a2z) : ((j & 4) ? a1h : a1z);
      float s = 0.f;
#pragma unroll
      for (int d = 0; d < 16; d++)
        s = fmaf(Wg[(h << 10) + (k << 4) + d], av[(h << 4) + d], s);
      w = s;
    }
    W16[idx] = (_Float16)w;
  }
  if (blockIdx.x == 0 && threadIdx.x < 128)
    biasC[threadIdx.x] =
        (threadIdx.x < 64) ? Zb[threadIdx.x] : Hb[threadIdx.x - 64];
}

// ---------------------------------------------------------------------------
// fp16 MFMA GEMM: [98304 x 64] @ [64 x 272], fp32 accumulate. A-frags from X
// (cvt in regs); B-frags from global W16 (L1/L2-resident). Wave = 16 rows x
// 17 col-tiles x K=64. Epilogue: per-wave LDS transpose (stride 68: 2-way
// bank alias = free) then 4 coalesced dwordx4 stores per buffer (16 lanes =
// one full 256 B row each).
__global__ __launch_bounds__(256) void mfma_gemm_k(
    const float* __restrict__ X, const _Float16* __restrict__ W16,
    const float* __restrict__ biasC,
    uint32_t* __restrict__ gbufF, uint32_t* __restrict__ gbufS,
    float* __restrict__ fbuf) {
  __shared__ uint32_t tr[4][16 * 68];   // per-wave 16 rows x 64 cols (+pad)
  const int tid = threadIdx.x;
  const int wv = tid >> 6, lane = tid & 63;
  const int m = lane & 15, quad = lane >> 4;
  const unsigned rw = blockIdx.x * 64 + wv * 16;      // wave's row base
  uint32_t* tw = tr[wv];

  const float* xr = X + (size_t)(rw + m) * 64;
  float4 x0 = *(const float4*)(xr + quad * 8);
  float4 x1 = *(const float4*)(xr + quad * 8 + 4);
  float4 x2 = *(const float4*)(xr + 32 + quad * 8);
  float4 x3 = *(const float4*)(xr + 32 + quad * 8 + 4);
  f16x8 A0 = {(_Float16)x0.x, (_Float16)x0.y, (_Float16)x0.z, (_Float16)x0.w,
              (_Float16)x1.x, (_Float16)x1.y, (_Float16)x1.z, (_Float16)x1.w};
  f16x8 A1 = {(_Float16)x2.x, (_Float16)x2.y, (_Float16)x2.z, (_Float16)x2.w,
              (_Float16)x3.x, (_Float16)x3.y, (_Float16)x3.z, (_Float16)x3.w};

  float bzc[4], bhc[4];
#pragma unroll
  for (int j = 0; j < 4; j++) {
    bzc[j] = biasC[j * 16 + m];
    bhc[j] = biasC[64 + j * 16 + m];
  }
  const int rsub = lane >> 4, chk = lane & 15;   // readback: row-sub, chunk

  f32x4 zacc[4], zs[4];
#pragma unroll
  for (int ct = 0; ct < 17; ct++) {
    const _Float16* wp = W16 + (ct * 16 + m) * 64;
    f16x8 B0 = *(const f16x8*)(wp + quad * 8);
    f16x8 B1 = *(const f16x8*)(wp + 32 + quad * 8);
    f32x4 acc = {0.f, 0.f, 0.f, 0.f};
    acc = __builtin_amdgcn_mfma_f32_16x16x32_f16(A0, B0, acc, 0, 0, 0);
    acc = __builtin_amdgcn_mfma_f32_16x16x32_f16(A1, B1, acc, 0, 0, 0);
    // C-layout: row = quad*4 + r, col = ct*16 + m  [measured: learn_hip m89]
    if (ct < 4) {
      zacc[ct] = acc;                        // z-feat tiles, saved for pairing
    } else if (ct < 8) {
      const int j = ct - 4;                  // h-feat tile -> pack {z,h}
#pragma unroll
      for (int r = 0; r < 4; r++) {
        f16x2 pv = {(_Float16)zacc[j][r], (_Float16)acc[r]};
        tw[(quad * 4 + r) * 68 + j * 16 + m] = __builtin_bit_cast(uint32_t, pv);
      }
      if (ct == 7) {   // full-tile readback: 4 stores x (16 lanes = 256B row)
#pragma unroll
        for (int i = 0; i < 4; i++) {
          int row = i * 4 + rsub;
          uint4 v = *(const uint4*)&tw[row * 68 + chk * 4];
          *(uint4*)&gbufF[(size_t)(rw + row) * 64 + chk * 4] = v;
        }
      }
    } else if (ct < 12) {
#pragma unroll
      for (int r = 0; r < 4; r++) zs[ct - 8][r] = acc[r] + bzc[ct - 8];
    } else if (ct < 16) {
      const int j = ct - 12;
#pragma unroll
      for (int r = 0; r < 4; r++) {
        f16x2 pv = {(_Float16)zs[j][r], (_Float16)(acc[r] + bhc[j])};
        tw[(quad * 4 + r) * 68 + j * 16 + m] = __builtin_bit_cast(uint32_t, pv);
      }
      if (ct == 15) {
#pragma unroll
        for (int i = 0; i < 4; i++) {
          int row = i * 4 + rsub;
          uint4 v = *(const uint4*)&tw[row * 68 + chk * 4];
          *(uint4*)&gbufS[(size_t)(rw + row) * 64 + chk * 4] = v;
        }
      }
    } else {
      const unsigned rb = rw + quad * 4;
#pragma unroll
      for (int r = 0; r < 4; r++) fbuf[(size_t)(rb + r) * 16 + m] = acc[r];
    }
  }
}

// ---------------------------------------------------------------------------
// Attention: one wave per (node, t) — the R10 configuration, which is the
// measured optimum (R5/R7/R11 all showed: trading occupancy/TLP for per-wave
// work-sharing loses in this gather kernel). Grid = (node-groups, t), x
// fastest, so co-resident blocks share one t-slab (L2-resident).
// Phase 1 (lane = neighbor, exec-masked): raw exp weights -> LDS.
// Phase 2 (lane = channel): 8-wide gather, in-loop norm sums, ELU + self.
// Output abuf is fp16-packed {zpre,hpre} (halves attn write + gru read).
__global__ __launch_bounds__(256) void attn_k(
    const uint32_t* __restrict__ gbufF, const uint32_t* __restrict__ gbufS,
    const float* __restrict__ fbuf,
    const int* __restrict__ adj, const int* __restrict__ deg,
    const float* __restrict__ bgz, const float* __restrict__ bgh,
    uint32_t* __restrict__ abuf) {
  __shared__ int adjL[4][MAXD];
  __shared__ float wexp[4][8][68];      // stride 68 kills head-alias
  const int tid = threadIdx.x;
  const int lane = tid & 63;
  const int ws = tid >> 6;
  const int node = blockIdx.x * 4 + ws;
  const int t = blockIdx.y;
  const int b = node >> 11;
  const int nl = node & (NN - 1);
  const int dg = deg[node];
  adjL[ws][lane] = (lane < dg) ? adj[node * MAXD + lane] : 0;
  const int dgp = (dg + 7) & ~7;        // padded slots have weight 0 -> inert

  const unsigned rb = (unsigned)(b * NT + t) * NN;
  const float* fb = fbuf + (size_t)rb * 16;
  const uint32_t* gF = gbufF + (size_t)rb * 64;
  const uint32_t* gS = gbufS + (size_t)rb * 64;
  const int ch = lane, hh = lane >> 4;

  // ---- phase 1: raw exp attention weights (lane = neighbor slot) ----
  {
    const float4* p = (const float4*)(fb + nl * 16);
    float4 f1z = p[0], f1h = p[1];
    if (lane < dg) {                    // exec-masked: inactive lanes load 0 B
      int mm = adjL[ws][lane];
      const float4* q = (const float4*)(fb + mm * 16);
      float4 f2z = q[2], f2h = q[3];
      wexp[ws][0][lane] = __expf(LR(f1z.x + f2z.x));
      wexp[ws][1][lane] = __expf(LR(f1z.y + f2z.y));
      wexp[ws][2][lane] = __expf(LR(f1z.z + f2z.z));
      wexp[ws][3][lane] = __expf(LR(f1z.w + f2z.w));
      wexp[ws][4][lane] = __expf(LR(f1h.x + f2h.x));
      wexp[ws][5][lane] = __expf(LR(f1h.y + f2h.y));
      wexp[ws][6][lane] = __expf(LR(f1h.z + f2h.z));
      wexp[ws][7][lane] = __expf(LR(f1h.w + f2h.w));
    } else {
#pragma unroll
      for (int k = 0; k < 8; k++) wexp[ws][k][lane] = 0.f;
    }
  }

  // ---- phase 2: 8-wide unrolled weighted gather, in-loop norm sums ----
  float az = 0.f, ah = 0.f, sz = 0.f, sh = 0.f;
  const float* wz = wexp[ws][hh];
  const float* wh = wexp[ws][4 + hh];
  for (int mi = 0; mi < dgp; mi += 8) {
    int4 ma = *(const int4*)&adjL[ws][mi];
    int4 mb = *(const int4*)&adjL[ws][mi + 4];
    float4 wza = *(const float4*)&wz[mi];
    float4 wzb = *(const float4*)&wz[mi + 4];
    float4 wha = *(const float4*)&wh[mi];
    float4 whb = *(const float4*)&wh[mi + 4];
    uint32_t d0 = gF[(ma.x << 6) + ch];
    uint32_t d1 = gF[(ma.y << 6) + ch];
    uint32_t d2 = gF[(ma.z << 6) + ch];
    uint32_t d3 = gF[(ma.w << 6) + ch];
    uint32_t d4 = gF[(mb.x << 6) + ch];
    uint32_t d5 = gF[(mb.y << 6) + ch];
    uint32_t d6 = gF[(mb.z << 6) + ch];
    uint32_t d7 = gF[(mb.w << 6) + ch];
    f16x2 p0 = __builtin_bit_cast(f16x2, d0);
    f16x2 p1 = __builtin_bit_cast(f16x2, d1);
    f16x2 p2 = __builtin_bit_cast(f16x2, d2);
    f16x2 p3 = __builtin_bit_cast(f16x2, d3);
    f16x2 p4 = __builtin_bit_cast(f16x2, d4);
    f16x2 p5 = __builtin_bit_cast(f16x2, d5);
    f16x2 p6 = __builtin_bit_cast(f16x2, d6);
    f16x2 p7 = __builtin_bit_cast(f16x2, d7);
    az = fmaf(wza.x, (float)p0.x, az); ah = fmaf(wha.x, (float)p0.y, ah);
    az = fmaf(wza.y, (float)p1.x, az); ah = fmaf(wha.y, (float)p1.y, ah);
    az = fmaf(wza.z, (float)p2.x, az); ah = fmaf(wha.z, (float)p2.y, ah);
    az = fmaf(wza.w, (float)p3.x, az); ah = fmaf(wha.w, (float)p3.y, ah);
    az = fmaf(wzb.x, (float)p4.x, az); ah = fmaf(whb.x, (float)p4.y, ah);
    az = fmaf(wzb.y, (float)p5.x, az); ah = fmaf(whb.y, (float)p5.y, ah);
    az = fmaf(wzb.z, (float)p6.x, az); ah = fmaf(whb.z, (float)p6.y, ah);
    az = fmaf(wzb.w, (float)p7.x, az); ah = fmaf(whb.w, (float)p7.y, ah);
    sz += (wza.x + wza.y) + (wza.z + wza.w) + (wzb.x + wzb.y) + (wzb.z + wzb.w);
    sh += (wha.x + wha.y) + (wha.z + wha.w) + (whb.x + whb.y) + (whb.z + whb.w);
  }
  az *= RCPF(sz);
  ah *= RCPF(sh);

  // ---- epilogue: ELU + bias + self -> fp16-packed pre-gate dword ----
  f16x2 sp = __builtin_bit_cast(f16x2, gS[(nl << 6) + ch]);
  float vz = az + bgz[ch]; vz = vz > 0.f ? vz : __expf(vz) - 1.f;
  float vh = ah + bgh[ch]; vh = vh > 0.f ? vh : __expf(vh) - 1.f;
  f16x2 pre = {(_Float16)(vz + (float)sp.x), (_Float16)(vh + (float)sp.y)};
  abuf[(size_t)(rb + nl) * 64 + ch] = __builtin_bit_cast(uint32_t, pre);
}

// ---------------------------------------------------------------------------
// GRU recurrence: one lane per (node, channel); 12-step serial chain on
// fp16-packed pre-gate values (25 MB coalesced read). BN fused at the end.
__global__ __launch_bounds__(256) void gru_k(
    const uint32_t* __restrict__ abuf,
    const float* __restrict__ gam, const float* __restrict__ bet,
    const float* __restrict__ mu, const float* __restrict__ var,
    float* __restrict__ out) {
  const int gtid = blockIdx.x * 256 + threadIdx.x;   // [0, NB*NN*64)
  const int node = gtid >> 6, ch = gtid & 63;
  const int b = node >> 11, nl = node & (NN - 1);
  float hc = 0.f;
#pragma unroll
  for (int t = 0; t < NT; t++) {
    f16x2 pre = __builtin_bit_cast(
        f16x2, abuf[(size_t)((b * NT + t) * NN + nl) * 64 + ch]);
    float zg = RCPF(1.f + __expf(-((float)pre.x + hc)));      // sigmoid
    float ta = (float)pre.y + hc;
    float tg = 1.f - 2.f * RCPF(__expf(2.f * ta) + 1.f);      // tanh
    hc = zg * hc + (1.f - zg) * tg;
  }
  out[gtid] = (hc - mu[ch]) * rsqrtf(var[ch] + 1e-3f) * gam[ch] + bet[ch];
}

// ---------------------------------------------------------------------------
extern "C" void kernel_launch(void* const* d_in, const int* in_sizes, int n_in,
                              void* d_out, int out_size, void* d_ws, size_t ws_size,
                              hipStream_t stream) {
  (void)in_sizes; (void)n_in; (void)out_size; (void)ws_size;
  const float* X   = (const float*)d_in[0];
  const float* bm  = (const float*)d_in[1];
  const float* Wz  = (const float*)d_in[2];
  const float* Zb  = (const float*)d_in[3];
  const float* Wh  = (const float*)d_in[4];
  const float* Hb  = (const float*)d_in[5];
  const float* Wgz = (const float*)d_in[6];
  const float* a1z = (const float*)d_in[7];
  const float* a2z = (const float*)d_in[8];
  const float* bgz = (const float*)d_in[9];
  const float* Wgh = (const float*)d_in[10];
  const float* a1h = (const float*)d_in[11];
  const float* a2h = (const float*)d_in[12];
  const float* bgh = (const float*)d_in[13];
  const float* gam = (const float*)d_in[14];
  const float* bet = (const float*)d_in[15];
  const float* mu  = (const float*)d_in[16];
  const float* var = (const float*)d_in[17];
  float* out = (float*)d_out;

  char* p = (char*)d_ws;
  uint32_t* gbufF = (uint32_t*)p; p += (size_t)NR * 64 * sizeof(uint32_t);  // 25 MB
  uint32_t* gbufS = (uint32_t*)p; p += (size_t)NR * 64 * sizeof(uint32_t);  // 25 MB
  float*    fbuf  = (float*)p;    p += (size_t)NR * 16 * sizeof(float);     // 6 MB
  uint32_t* abuf  = (uint32_t*)p; p += (size_t)NR * 64 * sizeof(uint32_t);  // 25 MB
  int*      adj   = (int*)p;      p += (size_t)NB * NN * MAXD * sizeof(int);// 2 MB
  int*      deg   = (int*)p;      p += (size_t)NB * NN * sizeof(int);       // 32 KB
  _Float16* W16   = (_Float16*)p; p += 272 * 64 * sizeof(_Float16);         // 34 KB
  float*    biasC = (float*)p;    p += 128 * sizeof(float);

  prep_w_k<<<dim3(68), dim3(256), 0, stream>>>(
      Wgz, Wgh, Wz, Wh, a1z, a2z, a1h, a2h, Zb, Hb, W16, biasC);
  build_adj_k<<<dim3(NB * NN / 4), dim3(256), 0, stream>>>(bm, adj, deg);
  mfma_gemm_k<<<dim3(NR / 64), dim3(256), 0, stream>>>(
      X, W16, biasC, gbufF, gbufS, fbuf);
  attn_k<<<dim3(NB * NN / 4, NT), dim3(256), 0, stream>>>(
      gbufF, gbufS, fbuf, adj, deg, bgz, bgh, abuf);
  gru_k<<<dim3(NB * NN * 64 / 256), dim3(256), 0, stream>>>(
      abuf, gam, bet, mu, var, out);
}